// Round 7
// baseline (377.773 us; speedup 1.0000x reference)
//
#include <hip/hip_runtime.h>
#include <math.h>

#define N_NODES 100000
#define N_EDGES 3200000
#define IN_DIM  128
#define HID     64
#define N_MTILE (N_NODES / 16)            // 6250 row-tiles (exact)

// binning-sort geometry
#define E_BLK    8192
#define NBLK_BIN ((N_EDGES + E_BLK - 1) / E_BLK)   // 391
#define BUCKETS  500
#define BRANGE   200                                // 500*200 = 100000 exact
#define MT_LEN   (BUCKETS * NBLK_BIN)               // 195500
#define NB_SA2   ((MT_LEN + 255) / 256)             // 764 scan blocks

typedef unsigned int  uint;
typedef unsigned short ushort_t;
typedef __attribute__((ext_vector_type(8))) short bf16x8;
typedef __attribute__((ext_vector_type(4))) float f32x4;

// HW packed f32->bf16 (RNE): lo -> bits[15:0], hi -> bits[31:16]
__device__ __forceinline__ uint cvtpk(float lo, float hi) {
    uint r;
    asm("v_cvt_pk_bf16_f32 %0, %1, %2" : "=v"(r) : "v"(lo), "v"(hi));
    return r;
}

// ---------------------------------------------------------------------------
// wrepack: lay W = [W1_l | W1_r] (128x128) out in per-lane B-fragment order
// for v_mfma_f32_16x16x32_bf16 (t=col-tile, s=k-step, l=lane, j=k-elem):
//   wpk[((t*4+s)*64+l)*8+j] = bf16( W[s*32+(l>>4)*8+j][t*16+(l&15)] )
// ---------------------------------------------------------------------------
__global__ __launch_bounds__(256) void wrepack(const float* __restrict__ Wl,
                                               const float* __restrict__ Wr,
                                               ushort_t* __restrict__ wpk) {
    const int idx = blockIdx.x * 256 + threadIdx.x;
    if (idx >= 128 * 128) return;
    const int j = idx & 7;
    const int l = (idx >> 3) & 63;
    const int s = (idx >> 9) & 3;
    const int t = idx >> 11;
    const int row = s * 32 + ((l >> 4) << 3) + j;
    const int col = t * 16 + (l & 15);
    const float v = (col < 64) ? Wl[row * 64 + col] : Wr[row * 64 + (col - 64)];
    uint a = __float_as_uint(v);
    a = (a + 0x7fffu + ((a >> 16) & 1u)) >> 16;
    wpk[idx] = (ushort_t)a;
}

// ---------------------------------------------------------------------------
// gemm1m: MFMA gemm, 1 row-tile per block (grid 6250), 4 waves = 8 col-tiles.
// A-tile staged through LDS (coalesced 4KB global loads, padded rows to
// avoid ds_read bank clustering). Waves 0,1 -> xlb (slice-major bf16),
// waves 2,3 -> xr (+b1, f32).
// xlb layout: xlb[slice][node][u], slice=col>>4 (4 planes of 3.2MB).
// ---------------------------------------------------------------------------
__global__ __launch_bounds__(256) void gemm1m(const float* __restrict__ x,
                                              const ushort_t* __restrict__ wpk,
                                              const float* __restrict__ b1,
                                              uint* __restrict__ xlb,
                                              float* __restrict__ xr) {
    __shared__ float ax[16][132];             // padded: 132 words/row
    const int tid  = threadIdx.x;
    const int wid  = tid >> 6;
    const int lane = tid & 63;
    const int t0   = wid * 2;
    const int r16  = lane & 15;   // A-row / C-col within tile
    const int kg   = lane >> 4;   // k-group

    bf16x8 bf[2][4];
    #pragma unroll
    for (int tt = 0; tt < 2; ++tt)
        #pragma unroll
        for (int s = 0; s < 4; ++s)
            bf[tt][s] = *(const bf16x8*)&wpk[(((size_t)(t0 + tt) * 4 + s) * 64 + lane) * 8];

    float bias[2] = {0.f, 0.f};
    if (wid >= 2) {
        bias[0] = b1[(t0 + 0) * 16 + r16 - 64];
        bias[1] = b1[(t0 + 1) * 16 + r16 - 64];
    }

    const int row0 = blockIdx.x * 16;

    // stage 16x128 f32 A-tile: 2 iters of fully-coalesced 4KB
    {
        const int r = tid >> 5;          // 0..7
        const int o = tid & 31;          // 16B unit within row
        #pragma unroll
        for (int it = 0; it < 2; ++it) {
            const int rr = it * 8 + r;
            const f32x4 g = *(const f32x4*)&x[(size_t)(row0 + rr) * IN_DIM + o * 4];
            *(f32x4*)&ax[rr][o * 4] = g;
        }
    }
    __syncthreads();

    f32x4 acc[2];
    acc[0] = (f32x4){0.f, 0.f, 0.f, 0.f};
    acc[1] = (f32x4){0.f, 0.f, 0.f, 0.f};

    #pragma unroll
    for (int s = 0; s < 4; ++s) {
        const float* lp = &ax[r16][s * 32 + kg * 8];
        const f32x4 a0 = *(const f32x4*)lp;
        const f32x4 a1 = *(const f32x4*)(lp + 4);
        union { uint u[4]; bf16x8 v; } af;
        af.u[0] = cvtpk(a0.x, a0.y);
        af.u[1] = cvtpk(a0.z, a0.w);
        af.u[2] = cvtpk(a1.x, a1.y);
        af.u[3] = cvtpk(a1.z, a1.w);
        acc[0] = __builtin_amdgcn_mfma_f32_16x16x32_bf16(af.v, bf[0][s], acc[0], 0, 0, 0);
        acc[1] = __builtin_amdgcn_mfma_f32_16x16x32_bf16(af.v, bf[1][s], acc[1], 0, 0, 0);
    }

    if (wid < 2) {
        #pragma unroll
        for (int tt = 0; tt < 2; ++tt) {
            const int slice = t0 + tt;             // 0..3
            #pragma unroll
            for (int r = 0; r < 4; ++r) {
                const float mine  = acc[tt][r];
                const float other = __shfl_xor(mine, 1);
                if ((r16 & 1) == 0) {
                    const int row = row0 + kg * 4 + r;
                    xlb[(size_t)slice * (N_NODES * 8) + (size_t)row * 8 + (r16 >> 1)]
                        = cvtpk(mine, other);
                }
            }
        }
    } else {
        #pragma unroll
        for (int tt = 0; tt < 2; ++tt) {
            const int c = (t0 + tt) * 16 + r16 - 64;
            #pragma unroll
            for (int r = 0; r < 4; ++r) {
                const int row = row0 + kg * 4 + r;
                xr[(size_t)row * HID + c] = acc[tt][r] + bias[tt];
            }
        }
    }
}

// ---------------------------------------------------------------------------
// binHist: per (edge-block, bucket) histogram via LDS atomics.
// MT is bucket-major: MT[b * NBLK_BIN + blk]
// ---------------------------------------------------------------------------
__global__ __launch_bounds__(256) void binHist(const int* __restrict__ ei,
                                               int* __restrict__ MT) {
    __shared__ int h[BUCKETS];
    for (int j = threadIdx.x; j < BUCKETS; j += 256) h[j] = 0;
    __syncthreads();
    const int e0 = blockIdx.x * E_BLK;
    const int e1 = min(e0 + E_BLK, N_EDGES);
    for (int e = e0 + threadIdx.x; e < e1; e += 256)
        atomicAdd(&h[ei[N_EDGES + e] / BRANGE], 1);
    __syncthreads();
    for (int j = threadIdx.x; j < BUCKETS; j += 256)
        MT[j * NBLK_BIN + blockIdx.x] = h[j];
}

// exclusive scan of MT (length MT_LEN) -> MTi, 3 small kernels
__global__ __launch_bounds__(256) void scanA2(const int* __restrict__ MT,
                                              int* __restrict__ MTi,
                                              int* __restrict__ partial) {
    __shared__ int sh[256];
    const int tid = threadIdx.x;
    const int gid = blockIdx.x * 256 + tid;
    int v = (gid < MT_LEN) ? MT[gid] : 0;
    sh[tid] = v;
    __syncthreads();
    for (int off = 1; off < 256; off <<= 1) {
        int t = (tid >= off) ? sh[tid - off] : 0;
        __syncthreads();
        sh[tid] += t;
        __syncthreads();
    }
    if (gid < MT_LEN) MTi[gid] = sh[tid];
    if (tid == 255) partial[blockIdx.x] = sh[255];
}

__global__ __launch_bounds__(1024) void scanB2(int* __restrict__ partial) {
    __shared__ int sh[1024];
    const int tid = threadIdx.x;
    int v = (tid < NB_SA2) ? partial[tid] : 0;
    sh[tid] = v;
    __syncthreads();
    for (int off = 1; off < 1024; off <<= 1) {
        int t = (tid >= off) ? sh[tid - off] : 0;
        __syncthreads();
        sh[tid] += t;
        __syncthreads();
    }
    if (tid < NB_SA2) partial[tid] = sh[tid] - v;   // exclusive
}

__global__ __launch_bounds__(256) void scanC2(const int* __restrict__ MT,
                                              int* __restrict__ MTi,
                                              const int* __restrict__ partial) {
    const int gid = blockIdx.x * 256 + threadIdx.x;
    if (gid >= MT_LEN) return;
    MTi[gid] = MTi[gid] + partial[blockIdx.x] - MT[gid];   // exclusive scan
}

// ---------------------------------------------------------------------------
// binScatter: write packed (dstLocal<<17 | src) into bucket-major segments.
// src < 2^17 (100000), dstLocal < 200 (8 bits). No global atomics.
// ---------------------------------------------------------------------------
__global__ __launch_bounds__(256) void binScatter(const int* __restrict__ ei,
                                                  const int* __restrict__ MTi,
                                                  uint* __restrict__ pairs) {
    __shared__ int cur[BUCKETS];
    for (int j = threadIdx.x; j < BUCKETS; j += 256)
        cur[j] = MTi[j * NBLK_BIN + blockIdx.x];
    __syncthreads();
    const int e0 = blockIdx.x * E_BLK;
    const int e1 = min(e0 + E_BLK, N_EDGES);
    for (int e = e0 + threadIdx.x; e < e1; e += 256) {
        const int dst = ei[N_EDGES + e];
        const int src = ei[e];
        const int bkt = dst / BRANGE;
        const int dl  = dst - bkt * BRANGE;
        const int pos = atomicAdd(&cur[bkt], 1);
        pairs[pos] = ((uint)dl << 17) | (uint)src;
    }
}

// ---------------------------------------------------------------------------
// bucketCSR: one block per bucket (200 nodes, ~6400 edges). LDS count+scan
// -> startA/cnt/deg_inv, then LDS-cursor scatter of src into final ssrc.
// ---------------------------------------------------------------------------
__global__ __launch_bounds__(256) void bucketCSR(const uint* __restrict__ pairs,
                                                 const int* __restrict__ MTi,
                                                 int* __restrict__ startA,
                                                 int* __restrict__ cnt,
                                                 float* __restrict__ deg_inv,
                                                 int* __restrict__ ssrc) {
    __shared__ int h[BRANGE];
    __shared__ int curs[BRANGE];
    __shared__ int sc[256];
    const int tid = threadIdx.x;
    const int b   = blockIdx.x;
    const int n0  = b * BRANGE;

    for (int j = tid; j < BRANGE; j += 256) h[j] = 0;
    __syncthreads();

    const int bs = MTi[b * NBLK_BIN];
    const int be = (b + 1 < BUCKETS) ? MTi[(b + 1) * NBLK_BIN] : N_EDGES;

    for (int e = bs + tid; e < be; e += 256)
        atomicAdd(&h[pairs[e] >> 17], 1);
    __syncthreads();

    sc[tid] = (tid < BRANGE) ? h[tid] : 0;
    __syncthreads();
    for (int off = 1; off < 256; off <<= 1) {
        int t = (tid >= off) ? sc[tid - off] : 0;
        __syncthreads();
        sc[tid] += t;
        __syncthreads();
    }
    if (tid < BRANGE) {
        const int c  = h[tid];
        const int st = bs + sc[tid] - c;   // exclusive
        const int node = n0 + tid;
        startA[node]  = st;
        cnt[node]     = c;
        deg_inv[node] = (c > 0) ? (1.0f / (float)c) : 0.0f;
        curs[tid]     = st;
    }
    __syncthreads();

    for (int e = bs + tid; e < be; e += 256) {
        const uint p = pairs[e];
        const int r = atomicAdd(&curs[p >> 17], 1);
        ssrc[r] = (int)(p & 0x1FFFFu);
    }
}

// ---------------------------------------------------------------------------
// agg1slice: one of 4 column-slice passes. Wave per node; lanes laid out as
// [8 edges x 8 uints]. Slice plane (3.2MB) stays L2-resident per XCD.
// Pass s computes cols [16s,16s+16): h = relu(sum*di + xr); accumulates
// partial W2 dots into hl/hr (s==0 stores, else RMW — wave owns node).
// ---------------------------------------------------------------------------
__global__ __launch_bounds__(256) void agg1slice(const int* __restrict__ start,
                                                 const int* __restrict__ cnt,
                                                 const int* __restrict__ ssrc,
                                                 const uint* __restrict__ xlb,
                                                 const float* __restrict__ xr,
                                                 const float* __restrict__ deg_inv,
                                                 const float* __restrict__ w2l,
                                                 const float* __restrict__ w2r,
                                                 const float* __restrict__ b2,
                                                 float* __restrict__ hl,
                                                 float* __restrict__ hr,
                                                 int s) {
    const int gid  = blockIdx.x * 256 + threadIdx.x;
    const int node = gid >> 6;
    const int lane = gid & 63;
    if (node >= N_NODES) return;

    const int st = start[node];
    const int c  = cnt[node];
    const int es = lane >> 3;   // edge slot 0..7
    const int u  = lane & 7;    // uint within slice row

    const uint* xs = xlb + (size_t)s * (N_NODES * 8);

    float sx = 0.f, sy = 0.f;
    for (int base = 0; base < c; base += 8) {
        const int idx = base + es;
        if (idx < c) {
            const int  src = ssrc[st + idx];          // 8-lane broadcast load
            const uint v   = xs[(size_t)src * 8 + u]; // 32B contiguous per edge
            sx += __uint_as_float(v << 16);
            sy += __uint_as_float(v & 0xffff0000u);
        }
    }
    // reduce over edge-slot axis
    sx += __shfl_xor(sx, 8);  sy += __shfl_xor(sy, 8);
    sx += __shfl_xor(sx, 16); sy += __shfl_xor(sy, 16);
    sx += __shfl_xor(sx, 32); sy += __shfl_xor(sy, 32);

    const float di  = deg_inv[node];
    const int   col = s * 16 + 2 * u;
    const float2 xv = *(const float2*)&xr[(size_t)node * HID + col];
    const float h0 = fmaxf(sx * di + xv.x, 0.f);
    const float h1 = fmaxf(sy * di + xv.y, 0.f);
    float a = h0 * w2l[col] + h1 * w2l[col + 1];
    float b = h0 * w2r[col] + h1 * w2r[col + 1];
    // reduce over u axis
    a += __shfl_xor(a, 1); b += __shfl_xor(b, 1);
    a += __shfl_xor(a, 2); b += __shfl_xor(b, 2);
    a += __shfl_xor(a, 4); b += __shfl_xor(b, 4);

    if (lane == 0) {
        if (s == 0) { hl[node] = a; hr[node] = b + b2[0]; }
        else        { hl[node] += a; hr[node] += b; }
    }
}

// ---------------------------------------------------------------------------
// agg2pull: wave per node. out = sigmoid(sum_j hl[j] * deg_inv + hr)
// ---------------------------------------------------------------------------
__global__ __launch_bounds__(256) void agg2pull(const int* __restrict__ start,
                                                const int* __restrict__ cnt,
                                                const int* __restrict__ sorted_src,
                                                const float* __restrict__ hl,
                                                const float* __restrict__ hr,
                                                const float* __restrict__ deg_inv,
                                                float* __restrict__ out) {
    const int gid  = blockIdx.x * 256 + threadIdx.x;
    const int node = gid >> 6;
    const int lane = gid & 63;
    if (node >= N_NODES) return;

    const int s = start[node];
    const int c = cnt[node];

    float sum = 0.0f;
    for (int j = lane; j < c; j += 64) {
        sum += hl[sorted_src[s + j]];
    }
    #pragma unroll
    for (int off = 32; off; off >>= 1) sum += __shfl_xor(sum, off);

    if (lane == 0) {
        const float z = sum * deg_inv[node] + hr[node];
        out[node] = 1.0f / (1.0f + expf(-z));
    }
}

extern "C" void kernel_launch(void* const* d_in, const int* in_sizes, int n_in,
                              void* d_out, int out_size, void* d_ws, size_t ws_size,
                              hipStream_t stream) {
    const float* x    = (const float*)d_in[0];
    const int*   ei   = (const int*)  d_in[1];
    const float* W1l  = (const float*)d_in[2];
    const float* b1   = (const float*)d_in[3];
    const float* W1r  = (const float*)d_in[4];
    const float* W2l  = (const float*)d_in[5];
    const float* b2   = (const float*)d_in[6];
    const float* W2r  = (const float*)d_in[7];
    float* out = (float*)d_out;

    char* wsb = (char*)d_ws;
    const size_t N = N_NODES;
    uint*     xlb     = (uint*)wsb;      wsb += 32 * N * 4;           // 4 slice planes
    float*    xr      = (float*)wsb;     wsb += 64 * N * 4;
    float*    hl      = (float*)wsb;     wsb += N * 4;
    float*    hr      = (float*)wsb;     wsb += N * 4;
    float*    deg_inv = (float*)wsb;     wsb += N * 4;
    int*      cnt     = (int*)wsb;       wsb += N * 4;
    int*      startA  = (int*)wsb;       wsb += N * 4;
    int*      MT      = (int*)wsb;       wsb += (size_t)MT_LEN * 4;
    int*      MTi     = (int*)wsb;       wsb += (size_t)MT_LEN * 4;
    int*      partial = (int*)wsb;       wsb += 1024 * 4;
    uint*     pairs   = (uint*)wsb;      wsb += (size_t)N_EDGES * 4;  // packed
    int*      ssrc    = (int*)wsb;       wsb += (size_t)N_EDGES * 4;
    ushort_t* wpk     = (ushort_t*)wsb;  wsb += 128 * 128 * 2;

    // dense path
    wrepack<<<64, 256, 0, stream>>>(W1l, W1r, wpk);
    gemm1m<<<N_MTILE, 256, 0, stream>>>(x, wpk, b1, xlb, xr);

    // CSR build, atomic-free (LDS only)
    binHist<<<NBLK_BIN, 256, 0, stream>>>(ei, MT);
    scanA2<<<NB_SA2, 256, 0, stream>>>(MT, MTi, partial);
    scanB2<<<1, 1024, 0, stream>>>(partial);
    scanC2<<<NB_SA2, 256, 0, stream>>>(MT, MTi, partial);
    binScatter<<<NBLK_BIN, 256, 0, stream>>>(ei, MTi, pairs);
    bucketCSR<<<BUCKETS, 256, 0, stream>>>(pairs, MTi, startA, cnt, deg_inv, ssrc);

    // layer-1 aggregation: 4 L2-resident column-slice passes
    {
        const long long total = (long long)N_NODES * 64;
        const int blocks = (int)((total + 255) / 256);
        for (int s = 0; s < 4; ++s)
            agg1slice<<<blocks, 256, 0, stream>>>(startA, cnt, ssrc, xlb, xr, deg_inv,
                                                  W2l, W2r, b2, hl, hr, s);
        agg2pull<<<blocks, 256, 0, stream>>>(startA, cnt, ssrc, hl, hr, deg_inv, out);
    }
}

// Round 8
// 299.140 us; speedup vs baseline: 1.2629x; 1.2629x over previous
//
#include <hip/hip_runtime.h>
#include <math.h>

#define N_NODES 100000
#define N_EDGES 3200000
#define IN_DIM  128
#define HID     64
#define N_MTILE (N_NODES / 16)            // 6250 row-tiles (exact)

// binning-sort geometry
#define E_BLK    8192
#define NBLK_BIN ((N_EDGES + E_BLK - 1) / E_BLK)   // 391
#define BUCKETS  500
#define BRANGE   200                                // 500*200 = 100000 exact
#define MT_LEN   (BUCKETS * NBLK_BIN)               // 195500
#define NB_SA2   ((MT_LEN + 255) / 256)             // 764 scan blocks

typedef unsigned int  uint;
typedef unsigned short ushort_t;
typedef __attribute__((ext_vector_type(8))) short bf16x8;
typedef __attribute__((ext_vector_type(4))) float f32x4;

// HW packed f32->bf16 (RNE): lo -> bits[15:0], hi -> bits[31:16]
__device__ __forceinline__ uint cvtpk(float lo, float hi) {
    uint r;
    asm("v_cvt_pk_bf16_f32 %0, %1, %2" : "=v"(r) : "v"(lo), "v"(hi));
    return r;
}

// ---------------------------------------------------------------------------
// wrepack: lay W = [W1_l | W1_r] (128x128) out in per-lane B-fragment order
// for v_mfma_f32_16x16x32_bf16 (t=col-tile, s=k-step, l=lane, j=k-elem):
//   wpk[((t*4+s)*64+l)*8+j] = bf16( W[s*32+(l>>4)*8+j][t*16+(l&15)] )
// ---------------------------------------------------------------------------
__global__ __launch_bounds__(256) void wrepack(const float* __restrict__ Wl,
                                               const float* __restrict__ Wr,
                                               ushort_t* __restrict__ wpk) {
    const int idx = blockIdx.x * 256 + threadIdx.x;
    if (idx >= 128 * 128) return;
    const int j = idx & 7;
    const int l = (idx >> 3) & 63;
    const int s = (idx >> 9) & 3;
    const int t = idx >> 11;
    const int row = s * 32 + ((l >> 4) << 3) + j;
    const int col = t * 16 + (l & 15);
    const float v = (col < 64) ? Wl[row * 64 + col] : Wr[row * 64 + (col - 64)];
    uint a = __float_as_uint(v);
    a = (a + 0x7fffu + ((a >> 16) & 1u)) >> 16;
    wpk[idx] = (ushort_t)a;
}

// ---------------------------------------------------------------------------
// gemm1m: MFMA gemm, 1 row-tile per block (grid 6250), 4 waves = 8 col-tiles.
// A-tile staged through LDS (coalesced 4KB loads, nontemporal — x is a pure
// stream). Waves 0,1 -> xlb (row-major bf16 pairs), waves 2,3 -> xr (+b1).
// ---------------------------------------------------------------------------
__global__ __launch_bounds__(256) void gemm1m(const float* __restrict__ x,
                                              const ushort_t* __restrict__ wpk,
                                              const float* __restrict__ b1,
                                              uint* __restrict__ xlb,
                                              float* __restrict__ xr) {
    __shared__ float ax[16][132];             // padded rows (132 words)
    const int tid  = threadIdx.x;
    const int wid  = tid >> 6;
    const int lane = tid & 63;
    const int t0   = wid * 2;
    const int r16  = lane & 15;   // A-row / C-col within tile
    const int kg   = lane >> 4;   // k-group

    bf16x8 bf[2][4];
    #pragma unroll
    for (int tt = 0; tt < 2; ++tt)
        #pragma unroll
        for (int s = 0; s < 4; ++s)
            bf[tt][s] = *(const bf16x8*)&wpk[(((size_t)(t0 + tt) * 4 + s) * 64 + lane) * 8];

    float bias[2] = {0.f, 0.f};
    if (wid >= 2) {
        bias[0] = b1[(t0 + 0) * 16 + r16 - 64];
        bias[1] = b1[(t0 + 1) * 16 + r16 - 64];
    }

    const int row0 = blockIdx.x * 16;

    // stage 16x128 f32 A-tile: 2 iters of fully-coalesced 4KB (nontemporal)
    {
        const int r = tid >> 5;          // 0..7
        const int o = tid & 31;          // 16B unit within row
        #pragma unroll
        for (int it = 0; it < 2; ++it) {
            const int rr = it * 8 + r;
            const f32x4 g = __builtin_nontemporal_load(
                (const f32x4*)&x[(size_t)(row0 + rr) * IN_DIM + o * 4]);
            *(f32x4*)&ax[rr][o * 4] = g;
        }
    }
    __syncthreads();

    f32x4 acc[2];
    acc[0] = (f32x4){0.f, 0.f, 0.f, 0.f};
    acc[1] = (f32x4){0.f, 0.f, 0.f, 0.f};

    #pragma unroll
    for (int s = 0; s < 4; ++s) {
        const float* lp = &ax[r16][s * 32 + kg * 8];
        const f32x4 a0 = *(const f32x4*)lp;
        const f32x4 a1 = *(const f32x4*)(lp + 4);
        union { uint u[4]; bf16x8 v; } af;
        af.u[0] = cvtpk(a0.x, a0.y);
        af.u[1] = cvtpk(a0.z, a0.w);
        af.u[2] = cvtpk(a1.x, a1.y);
        af.u[3] = cvtpk(a1.z, a1.w);
        acc[0] = __builtin_amdgcn_mfma_f32_16x16x32_bf16(af.v, bf[0][s], acc[0], 0, 0, 0);
        acc[1] = __builtin_amdgcn_mfma_f32_16x16x32_bf16(af.v, bf[1][s], acc[1], 0, 0, 0);
    }

    if (wid < 2) {
        #pragma unroll
        for (int tt = 0; tt < 2; ++tt) {
            const int col = (t0 + tt) * 16 + r16;
            #pragma unroll
            for (int r = 0; r < 4; ++r) {
                const float mine  = acc[tt][r];
                const float other = __shfl_xor(mine, 1);
                if ((lane & 1) == 0) {
                    const int row = row0 + kg * 4 + r;
                    xlb[(size_t)row * 32 + (col >> 1)] = cvtpk(mine, other);
                }
            }
        }
    } else {
        #pragma unroll
        for (int tt = 0; tt < 2; ++tt) {
            const int c = (t0 + tt) * 16 + r16 - 64;
            #pragma unroll
            for (int r = 0; r < 4; ++r) {
                const int row = row0 + kg * 4 + r;
                xr[(size_t)row * HID + c] = acc[tt][r] + bias[tt];
            }
        }
    }
}

// ---------------------------------------------------------------------------
// binHist: per (edge-block, bucket) histogram via LDS atomics.
// ---------------------------------------------------------------------------
__global__ __launch_bounds__(256) void binHist(const int* __restrict__ ei,
                                               int* __restrict__ MT) {
    __shared__ int h[BUCKETS];
    for (int j = threadIdx.x; j < BUCKETS; j += 256) h[j] = 0;
    __syncthreads();
    const int e0 = blockIdx.x * E_BLK;
    const int e1 = min(e0 + E_BLK, N_EDGES);
    for (int e = e0 + threadIdx.x; e < e1; e += 256)
        atomicAdd(&h[__builtin_nontemporal_load(&ei[N_EDGES + e]) / BRANGE], 1);
    __syncthreads();
    for (int j = threadIdx.x; j < BUCKETS; j += 256)
        MT[j * NBLK_BIN + blockIdx.x] = h[j];
}

// exclusive scan of MT (length MT_LEN) -> MTi, 3 small kernels
__global__ __launch_bounds__(256) void scanA2(const int* __restrict__ MT,
                                              int* __restrict__ MTi,
                                              int* __restrict__ partial) {
    __shared__ int sh[256];
    const int tid = threadIdx.x;
    const int gid = blockIdx.x * 256 + tid;
    int v = (gid < MT_LEN) ? MT[gid] : 0;
    sh[tid] = v;
    __syncthreads();
    for (int off = 1; off < 256; off <<= 1) {
        int t = (tid >= off) ? sh[tid - off] : 0;
        __syncthreads();
        sh[tid] += t;
        __syncthreads();
    }
    if (gid < MT_LEN) MTi[gid] = sh[tid];
    if (tid == 255) partial[blockIdx.x] = sh[255];
}

__global__ __launch_bounds__(1024) void scanB2(int* __restrict__ partial) {
    __shared__ int sh[1024];
    const int tid = threadIdx.x;
    int v = (tid < NB_SA2) ? partial[tid] : 0;
    sh[tid] = v;
    __syncthreads();
    for (int off = 1; off < 1024; off <<= 1) {
        int t = (tid >= off) ? sh[tid - off] : 0;
        __syncthreads();
        sh[tid] += t;
        __syncthreads();
    }
    if (tid < NB_SA2) partial[tid] = sh[tid] - v;   // exclusive
}

__global__ __launch_bounds__(256) void scanC2(const int* __restrict__ MT,
                                              int* __restrict__ MTi,
                                              const int* __restrict__ partial) {
    const int gid = blockIdx.x * 256 + threadIdx.x;
    if (gid >= MT_LEN) return;
    MTi[gid] = MTi[gid] + partial[blockIdx.x] - MT[gid];   // exclusive scan
}

// ---------------------------------------------------------------------------
// binScatter: write packed (dstLocal<<17 | src) into bucket-major segments.
// ---------------------------------------------------------------------------
__global__ __launch_bounds__(256) void binScatter(const int* __restrict__ ei,
                                                  const int* __restrict__ MTi,
                                                  uint* __restrict__ pairs) {
    __shared__ int cur[BUCKETS];
    for (int j = threadIdx.x; j < BUCKETS; j += 256)
        cur[j] = MTi[j * NBLK_BIN + blockIdx.x];
    __syncthreads();
    const int e0 = blockIdx.x * E_BLK;
    const int e1 = min(e0 + E_BLK, N_EDGES);
    for (int e = e0 + threadIdx.x; e < e1; e += 256) {
        const int dst = __builtin_nontemporal_load(&ei[N_EDGES + e]);
        const int src = __builtin_nontemporal_load(&ei[e]);
        const int bkt = dst / BRANGE;
        const int dl  = dst - bkt * BRANGE;
        const int pos = atomicAdd(&cur[bkt], 1);
        __builtin_nontemporal_store(((uint)dl << 17) | (uint)src, &pairs[pos]);
    }
}

// ---------------------------------------------------------------------------
// bucketCSR: one block per bucket (200 nodes, ~6400 edges). LDS count+scan
// -> startA/cnt/deg_inv, then LDS-cursor scatter of src into final ssrc.
// ---------------------------------------------------------------------------
__global__ __launch_bounds__(256) void bucketCSR(const uint* __restrict__ pairs,
                                                 const int* __restrict__ MTi,
                                                 int* __restrict__ startA,
                                                 int* __restrict__ cnt,
                                                 float* __restrict__ deg_inv,
                                                 int* __restrict__ ssrc) {
    __shared__ int h[BRANGE];
    __shared__ int curs[BRANGE];
    __shared__ int sc[256];
    const int tid = threadIdx.x;
    const int b   = blockIdx.x;
    const int n0  = b * BRANGE;

    for (int j = tid; j < BRANGE; j += 256) h[j] = 0;
    __syncthreads();

    const int bs = MTi[b * NBLK_BIN];
    const int be = (b + 1 < BUCKETS) ? MTi[(b + 1) * NBLK_BIN] : N_EDGES;

    for (int e = bs + tid; e < be; e += 256)
        atomicAdd(&h[__builtin_nontemporal_load(&pairs[e]) >> 17], 1);
    __syncthreads();

    sc[tid] = (tid < BRANGE) ? h[tid] : 0;
    __syncthreads();
    for (int off = 1; off < 256; off <<= 1) {
        int t = (tid >= off) ? sc[tid - off] : 0;
        __syncthreads();
        sc[tid] += t;
        __syncthreads();
    }
    if (tid < BRANGE) {
        const int c  = h[tid];
        const int st = bs + sc[tid] - c;   // exclusive
        const int node = n0 + tid;
        startA[node]  = st;
        cnt[node]     = c;
        deg_inv[node] = (c > 0) ? (1.0f / (float)c) : 0.0f;
        curs[tid]     = st;
    }
    __syncthreads();

    for (int e = bs + tid; e < be; e += 256) {
        const uint p = __builtin_nontemporal_load(&pairs[e]);
        const int r = atomicAdd(&curs[p >> 17], 1);
        ssrc[r] = (int)(p & 0x1FFFFu);
    }
}

// ---------------------------------------------------------------------------
// agg1pull: wave per node; lane = es*16+u, 4 edges in flight per iteration,
// uint2 (8B) gather per lane. Streams (ssrc) nontemporal so the 12.8MB xlb
// gather table keeps L2. Fused epilogue: h = relu(sum*di + xr);
// hl = h.W2_l; hr = h.W2_r + b2.
// ---------------------------------------------------------------------------
__global__ __launch_bounds__(256) void agg1pull(const int* __restrict__ start,
                                                const int* __restrict__ cnt,
                                                const int* __restrict__ ssrc,
                                                const uint2* __restrict__ xlb2,
                                                const float* __restrict__ xr,
                                                const float* __restrict__ deg_inv,
                                                const float* __restrict__ w2l,
                                                const float* __restrict__ w2r,
                                                const float* __restrict__ b2,
                                                float* __restrict__ hl,
                                                float* __restrict__ hr) {
    const int gid  = blockIdx.x * 256 + threadIdx.x;
    const int node = gid >> 6;
    const int lane = gid & 63;
    if (node >= N_NODES) return;

    const int s  = start[node];
    const int c  = cnt[node];
    const int es = lane >> 4;   // edge slot 0..3
    const int u  = lane & 15;   // uint2 index within 128B row

    float a0 = 0.f, a1 = 0.f, a2 = 0.f, a3 = 0.f;
    for (int base = 0; base < c; base += 64) {
        const int m = min(c - base, 64);
        int my = 0;
        if (lane < m) my = __builtin_nontemporal_load(&ssrc[s + base + lane]);
        for (int jj = 0; jj < m; jj += 4) {
            const int idx  = jj + es;
            const int srcp = __shfl(my, idx < 64 ? idx : 63);
            if (idx < m) {
                const uint2 v = xlb2[(size_t)srcp * 16 + u];
                a0 += __uint_as_float(v.x << 16);
                a1 += __uint_as_float(v.x & 0xffff0000u);
                a2 += __uint_as_float(v.y << 16);
                a3 += __uint_as_float(v.y & 0xffff0000u);
            }
        }
    }
    // fold edge-slot axis (bits 4,5 of lane)
    a0 += __shfl_xor(a0, 16); a1 += __shfl_xor(a1, 16);
    a2 += __shfl_xor(a2, 16); a3 += __shfl_xor(a3, 16);
    a0 += __shfl_xor(a0, 32); a1 += __shfl_xor(a1, 32);
    a2 += __shfl_xor(a2, 32); a3 += __shfl_xor(a3, 32);

    const float di = deg_inv[node];
    const f32x4 xv = *(const f32x4*)&xr[(size_t)node * HID + 4 * u];
    const float h0 = fmaxf(a0 * di + xv.x, 0.f);
    const float h1 = fmaxf(a1 * di + xv.y, 0.f);
    const float h2 = fmaxf(a2 * di + xv.z, 0.f);
    const float h3 = fmaxf(a3 * di + xv.w, 0.f);
    const f32x4 wl = *(const f32x4*)&w2l[4 * u];
    const f32x4 wr = *(const f32x4*)&w2r[4 * u];
    float a = h0 * wl.x + h1 * wl.y + h2 * wl.z + h3 * wl.w;
    float b = h0 * wr.x + h1 * wr.y + h2 * wr.z + h3 * wr.w;
    // fold u axis (bits 0..3)
    a += __shfl_xor(a, 1); b += __shfl_xor(b, 1);
    a += __shfl_xor(a, 2); b += __shfl_xor(b, 2);
    a += __shfl_xor(a, 4); b += __shfl_xor(b, 4);
    a += __shfl_xor(a, 8); b += __shfl_xor(b, 8);

    if (lane == 0) {
        hl[node] = a;
        hr[node] = b + b2[0];
    }
}

// ---------------------------------------------------------------------------
// agg2pull: wave per node. out = sigmoid(sum_j hl[j] * deg_inv + hr)
// ---------------------------------------------------------------------------
__global__ __launch_bounds__(256) void agg2pull(const int* __restrict__ start,
                                                const int* __restrict__ cnt,
                                                const int* __restrict__ sorted_src,
                                                const float* __restrict__ hl,
                                                const float* __restrict__ hr,
                                                const float* __restrict__ deg_inv,
                                                float* __restrict__ out) {
    const int gid  = blockIdx.x * 256 + threadIdx.x;
    const int node = gid >> 6;
    const int lane = gid & 63;
    if (node >= N_NODES) return;

    const int s = start[node];
    const int c = cnt[node];

    float sum = 0.0f;
    for (int j = lane; j < c; j += 64) {
        sum += hl[__builtin_nontemporal_load(&sorted_src[s + j])];
    }
    #pragma unroll
    for (int off = 32; off; off >>= 1) sum += __shfl_xor(sum, off);

    if (lane == 0) {
        const float z = sum * deg_inv[node] + hr[node];
        out[node] = 1.0f / (1.0f + expf(-z));
    }
}

extern "C" void kernel_launch(void* const* d_in, const int* in_sizes, int n_in,
                              void* d_out, int out_size, void* d_ws, size_t ws_size,
                              hipStream_t stream) {
    const float* x    = (const float*)d_in[0];
    const int*   ei   = (const int*)  d_in[1];
    const float* W1l  = (const float*)d_in[2];
    const float* b1   = (const float*)d_in[3];
    const float* W1r  = (const float*)d_in[4];
    const float* W2l  = (const float*)d_in[5];
    const float* b2   = (const float*)d_in[6];
    const float* W2r  = (const float*)d_in[7];
    float* out = (float*)d_out;

    char* wsb = (char*)d_ws;
    const size_t N = N_NODES;
    uint*     xlb     = (uint*)wsb;      wsb += 32 * N * 4;
    float*    xr      = (float*)wsb;     wsb += 64 * N * 4;
    float*    hl      = (float*)wsb;     wsb += N * 4;
    float*    hr      = (float*)wsb;     wsb += N * 4;
    float*    deg_inv = (float*)wsb;     wsb += N * 4;
    int*      cnt     = (int*)wsb;       wsb += N * 4;
    int*      startA  = (int*)wsb;       wsb += N * 4;
    int*      MT      = (int*)wsb;       wsb += (size_t)MT_LEN * 4;
    int*      MTi     = (int*)wsb;       wsb += (size_t)MT_LEN * 4;
    int*      partial = (int*)wsb;       wsb += 1024 * 4;
    uint*     pairs   = (uint*)wsb;      wsb += (size_t)N_EDGES * 4;
    int*      ssrc    = (int*)wsb;       wsb += (size_t)N_EDGES * 4;
    ushort_t* wpk     = (ushort_t*)wsb;  wsb += 128 * 128 * 2;

    // dense path
    wrepack<<<64, 256, 0, stream>>>(W1l, W1r, wpk);
    gemm1m<<<N_MTILE, 256, 0, stream>>>(x, wpk, b1, xlb, xr);

    // CSR build, atomic-free (LDS only)
    binHist<<<NBLK_BIN, 256, 0, stream>>>(ei, MT);
    scanA2<<<NB_SA2, 256, 0, stream>>>(MT, MTi, partial);
    scanB2<<<1, 1024, 0, stream>>>(partial);
    scanC2<<<NB_SA2, 256, 0, stream>>>(MT, MTi, partial);
    binScatter<<<NBLK_BIN, 256, 0, stream>>>(ei, MTi, pairs);
    bucketCSR<<<BUCKETS, 256, 0, stream>>>(pairs, MTi, startA, cnt, deg_inv, ssrc);

    // pull-aggregations
    {
        const long long total = (long long)N_NODES * 64;
        const int blocks = (int)((total + 255) / 256);
        agg1pull<<<blocks, 256, 0, stream>>>(startA, cnt, ssrc, (const uint2*)xlb,
                                             xr, deg_inv, W2l, W2r, b2, hl, hr);
        agg2pull<<<blocks, 256, 0, stream>>>(startA, cnt, ssrc, hl, hr, deg_inv, out);
    }
}

// Round 9
// 221.318 us; speedup vs baseline: 1.7069x; 1.3516x over previous
//
#include <hip/hip_runtime.h>
#include <math.h>

#define N_NODES 100000
#define N_EDGES 3200000
#define IN_DIM  128
#define HID     64
#define N_MTILE (N_NODES / 16)            // 6250 row-tiles (exact)

// binning-sort geometry
#define E_BLK    4096
#define NBLK_BIN ((N_EDGES + E_BLK - 1) / E_BLK)   // 782
#define BUCKETS  500
#define BRANGE   200                                // 500*200 = 100000 exact
#define MT_LEN   (BUCKETS * NBLK_BIN)               // 391000
#define NB_SA2   ((MT_LEN + 255) / 256)             // 1528 scan blocks (<=2048)

typedef unsigned int  uint;
typedef unsigned short ushort_t;
typedef __attribute__((ext_vector_type(8))) short bf16x8;
typedef __attribute__((ext_vector_type(4))) float f32x4;

// HW packed f32->bf16 (RNE): lo -> bits[15:0], hi -> bits[31:16]
__device__ __forceinline__ uint cvtpk(float lo, float hi) {
    uint r;
    asm("v_cvt_pk_bf16_f32 %0, %1, %2" : "=v"(r) : "v"(lo), "v"(hi));
    return r;
}

// ---------------------------------------------------------------------------
// wrepack: lay W = [W1_l | W1_r] (128x128) out in per-lane B-fragment order
// ---------------------------------------------------------------------------
__global__ __launch_bounds__(256) void wrepack(const float* __restrict__ Wl,
                                               const float* __restrict__ Wr,
                                               ushort_t* __restrict__ wpk) {
    const int idx = blockIdx.x * 256 + threadIdx.x;
    if (idx >= 128 * 128) return;
    const int j = idx & 7;
    const int l = (idx >> 3) & 63;
    const int s = (idx >> 9) & 3;
    const int t = idx >> 11;
    const int row = s * 32 + ((l >> 4) << 3) + j;
    const int col = t * 16 + (l & 15);
    const float v = (col < 64) ? Wl[row * 64 + col] : Wr[row * 64 + (col - 64)];
    uint a = __float_as_uint(v);
    a = (a + 0x7fffu + ((a >> 16) & 1u)) >> 16;
    wpk[idx] = (ushort_t)a;
}

// ---------------------------------------------------------------------------
// gemm1m: MFMA gemm, 1 row-tile per block, 4 waves = 8 col-tiles.
// ---------------------------------------------------------------------------
__global__ __launch_bounds__(256) void gemm1m(const float* __restrict__ x,
                                              const ushort_t* __restrict__ wpk,
                                              const float* __restrict__ b1,
                                              uint* __restrict__ xlb,
                                              float* __restrict__ xr) {
    __shared__ float ax[16][132];
    const int tid  = threadIdx.x;
    const int wid  = tid >> 6;
    const int lane = tid & 63;
    const int t0   = wid * 2;
    const int r16  = lane & 15;
    const int kg   = lane >> 4;

    bf16x8 bf[2][4];
    #pragma unroll
    for (int tt = 0; tt < 2; ++tt)
        #pragma unroll
        for (int s = 0; s < 4; ++s)
            bf[tt][s] = *(const bf16x8*)&wpk[(((size_t)(t0 + tt) * 4 + s) * 64 + lane) * 8];

    float bias[2] = {0.f, 0.f};
    if (wid >= 2) {
        bias[0] = b1[(t0 + 0) * 16 + r16 - 64];
        bias[1] = b1[(t0 + 1) * 16 + r16 - 64];
    }

    const int row0 = blockIdx.x * 16;

    {
        const int r = tid >> 5;
        const int o = tid & 31;
        #pragma unroll
        for (int it = 0; it < 2; ++it) {
            const int rr = it * 8 + r;
            const f32x4 g = __builtin_nontemporal_load(
                (const f32x4*)&x[(size_t)(row0 + rr) * IN_DIM + o * 4]);
            *(f32x4*)&ax[rr][o * 4] = g;
        }
    }
    __syncthreads();

    f32x4 acc[2];
    acc[0] = (f32x4){0.f, 0.f, 0.f, 0.f};
    acc[1] = (f32x4){0.f, 0.f, 0.f, 0.f};

    #pragma unroll
    for (int s = 0; s < 4; ++s) {
        const float* lp = &ax[r16][s * 32 + kg * 8];
        const f32x4 a0 = *(const f32x4*)lp;
        const f32x4 a1 = *(const f32x4*)(lp + 4);
        union { uint u[4]; bf16x8 v; } af;
        af.u[0] = cvtpk(a0.x, a0.y);
        af.u[1] = cvtpk(a0.z, a0.w);
        af.u[2] = cvtpk(a1.x, a1.y);
        af.u[3] = cvtpk(a1.z, a1.w);
        acc[0] = __builtin_amdgcn_mfma_f32_16x16x32_bf16(af.v, bf[0][s], acc[0], 0, 0, 0);
        acc[1] = __builtin_amdgcn_mfma_f32_16x16x32_bf16(af.v, bf[1][s], acc[1], 0, 0, 0);
    }

    if (wid < 2) {
        #pragma unroll
        for (int tt = 0; tt < 2; ++tt) {
            const int col = (t0 + tt) * 16 + r16;
            #pragma unroll
            for (int r = 0; r < 4; ++r) {
                const float mine  = acc[tt][r];
                const float other = __shfl_xor(mine, 1);
                if ((lane & 1) == 0) {
                    const int row = row0 + kg * 4 + r;
                    xlb[(size_t)row * 32 + (col >> 1)] = cvtpk(mine, other);
                }
            }
        }
    } else {
        #pragma unroll
        for (int tt = 0; tt < 2; ++tt) {
            const int c = (t0 + tt) * 16 + r16 - 64;
            #pragma unroll
            for (int r = 0; r < 4; ++r) {
                const int row = row0 + kg * 4 + r;
                xr[(size_t)row * HID + c] = acc[tt][r] + bias[tt];
            }
        }
    }
}

// ---------------------------------------------------------------------------
// binHist: per (edge-block, bucket) histogram via LDS atomics.
// ---------------------------------------------------------------------------
__global__ __launch_bounds__(256) void binHist(const int* __restrict__ ei,
                                               int* __restrict__ MT) {
    __shared__ int h[BUCKETS];
    for (int j = threadIdx.x; j < BUCKETS; j += 256) h[j] = 0;
    __syncthreads();
    const int e0 = blockIdx.x * E_BLK;
    const int e1 = min(e0 + E_BLK, N_EDGES);
    for (int e = e0 + threadIdx.x; e < e1; e += 256)
        atomicAdd(&h[__builtin_nontemporal_load(&ei[N_EDGES + e]) / BRANGE], 1);
    __syncthreads();
    for (int j = threadIdx.x; j < BUCKETS; j += 256)
        MT[j * NBLK_BIN + blockIdx.x] = h[j];
}

// exclusive scan of MT (length MT_LEN) -> MTi
__global__ __launch_bounds__(256) void scanA2(const int* __restrict__ MT,
                                              int* __restrict__ MTi,
                                              int* __restrict__ partial) {
    __shared__ int sh[256];
    const int tid = threadIdx.x;
    const int gid = blockIdx.x * 256 + tid;
    int v = (gid < MT_LEN) ? MT[gid] : 0;
    sh[tid] = v;
    __syncthreads();
    for (int off = 1; off < 256; off <<= 1) {
        int t = (tid >= off) ? sh[tid - off] : 0;
        __syncthreads();
        sh[tid] += t;
        __syncthreads();
    }
    if (gid < MT_LEN) MTi[gid] = sh[tid];
    if (tid == 255) partial[blockIdx.x] = sh[255];
}

// 2-per-thread scan: capacity 2048 partials
__global__ __launch_bounds__(1024) void scanB2(int* __restrict__ partial) {
    __shared__ int sh[1024];
    const int tid = threadIdx.x;
    const int i0 = 2 * tid, i1 = 2 * tid + 1;
    int v0 = (i0 < NB_SA2) ? partial[i0] : 0;
    int v1 = (i1 < NB_SA2) ? partial[i1] : 0;
    const int s = v0 + v1;
    sh[tid] = s;
    __syncthreads();
    for (int off = 1; off < 1024; off <<= 1) {
        int t = (tid >= off) ? sh[tid - off] : 0;
        __syncthreads();
        sh[tid] += t;
        __syncthreads();
    }
    const int excl = sh[tid] - s;
    if (i0 < NB_SA2) partial[i0] = excl;
    if (i1 < NB_SA2) partial[i1] = excl + v0;
}

__global__ __launch_bounds__(256) void scanC2(const int* __restrict__ MT,
                                              int* __restrict__ MTi,
                                              const int* __restrict__ partial) {
    const int gid = blockIdx.x * 256 + threadIdx.x;
    if (gid >= MT_LEN) return;
    MTi[gid] = MTi[gid] + partial[blockIdx.x] - MT[gid];   // exclusive scan
}

// ---------------------------------------------------------------------------
// binScatter (staged): block-local counting sort in LDS, then each bucket's
// run written out contiguously (coalesced). No global atomics, no scattered
// 4B stores. 16 edges/thread, fully unrolled (register-resident).
// ---------------------------------------------------------------------------
__global__ __launch_bounds__(256) void binScatter(const int* __restrict__ ei,
                                                  const int* __restrict__ MTi,
                                                  uint* __restrict__ pairs) {
    __shared__ int  hcnt[BUCKETS];
    __shared__ int  lbase[BUCKETS + 1];
    __shared__ int  gbase[BUCKETS];
    __shared__ uint staged[E_BLK];
    __shared__ int  sc[256];

    const int tid = threadIdx.x;
    const int e0  = blockIdx.x * E_BLK;
    const int e1  = min(e0 + E_BLK, N_EDGES);
    const int n   = e1 - e0;

    for (int j = tid; j < BUCKETS; j += 256) {
        hcnt[j]  = 0;
        gbase[j] = MTi[j * NBLK_BIN + blockIdx.x];
    }
    __syncthreads();

    // pass 1: load edges, count, remember rank (all register-resident)
    uint pk[16]; int bk[16]; int rk[16];
    #pragma unroll
    for (int k = 0; k < 16; ++k) {
        const int e = e0 + k * 256 + tid;
        pk[k] = 0; bk[k] = -1; rk[k] = 0;
        if (e < e1) {
            const int dst = __builtin_nontemporal_load(&ei[N_EDGES + e]);
            const int src = __builtin_nontemporal_load(&ei[e]);
            const int bkt = dst / BRANGE;
            pk[k] = ((uint)(dst - bkt * BRANGE) << 17) | (uint)src;
            bk[k] = bkt;
            rk[k] = atomicAdd(&hcnt[bkt], 1);
        }
    }
    __syncthreads();

    // exclusive scan of hcnt[0..499] (2 per thread over 256 lanes)
    {
        int v0 = 0, v1 = 0;
        if (tid < 250) { v0 = hcnt[2 * tid]; v1 = hcnt[2 * tid + 1]; }
        const int s = v0 + v1;
        sc[tid] = s;
        __syncthreads();
        for (int off = 1; off < 256; off <<= 1) {
            int t = (tid >= off) ? sc[tid - off] : 0;
            __syncthreads();
            sc[tid] += t;
            __syncthreads();
        }
        const int excl = sc[tid] - s;
        if (tid < 250) {
            lbase[2 * tid]     = excl;
            lbase[2 * tid + 1] = excl + v0;
        }
        if (tid == 0) lbase[BUCKETS] = n;
    }
    __syncthreads();

    // pass 2: place into staged buffer grouped by bucket
    #pragma unroll
    for (int k = 0; k < 16; ++k) {
        if (bk[k] >= 0) staged[lbase[bk[k]] + rk[k]] = pk[k];
    }
    __syncthreads();

    // write-out: consecutive t -> consecutive dest within a bucket run
    for (int t = tid; t < n; t += 256) {
        int lo = 0, hi = BUCKETS;
        while (hi - lo > 1) {
            const int mid = (lo + hi) >> 1;
            if (lbase[mid] <= t) lo = mid; else hi = mid;
        }
        const int dest = gbase[lo] + (t - lbase[lo]);
        __builtin_nontemporal_store(staged[t], &pairs[dest]);
    }
}

// ---------------------------------------------------------------------------
// bucketCSR: one block per bucket (200 nodes). LDS count+scan -> startA/cnt/
// deg_inv, then LDS-cursor scatter of src into final ssrc.
// ---------------------------------------------------------------------------
__global__ __launch_bounds__(256) void bucketCSR(const uint* __restrict__ pairs,
                                                 const int* __restrict__ MTi,
                                                 int* __restrict__ startA,
                                                 int* __restrict__ cnt,
                                                 float* __restrict__ deg_inv,
                                                 int* __restrict__ ssrc) {
    __shared__ int h[BRANGE];
    __shared__ int curs[BRANGE];
    __shared__ int sc[256];
    const int tid = threadIdx.x;
    const int b   = blockIdx.x;
    const int n0  = b * BRANGE;

    for (int j = tid; j < BRANGE; j += 256) h[j] = 0;
    __syncthreads();

    const int bs = MTi[b * NBLK_BIN];
    const int be = (b + 1 < BUCKETS) ? MTi[(b + 1) * NBLK_BIN] : N_EDGES;

    for (int e = bs + tid; e < be; e += 256)
        atomicAdd(&h[__builtin_nontemporal_load(&pairs[e]) >> 17], 1);
    __syncthreads();

    sc[tid] = (tid < BRANGE) ? h[tid] : 0;
    __syncthreads();
    for (int off = 1; off < 256; off <<= 1) {
        int t = (tid >= off) ? sc[tid - off] : 0;
        __syncthreads();
        sc[tid] += t;
        __syncthreads();
    }
    if (tid < BRANGE) {
        const int c  = h[tid];
        const int st = bs + sc[tid] - c;   // exclusive
        const int node = n0 + tid;
        startA[node]  = st;
        cnt[node]     = c;
        deg_inv[node] = (c > 0) ? (1.0f / (float)c) : 0.0f;
        curs[tid]     = st;
    }
    __syncthreads();

    for (int e = bs + tid; e < be; e += 256) {
        const uint p = __builtin_nontemporal_load(&pairs[e]);
        const int r = atomicAdd(&curs[p >> 17], 1);
        ssrc[r] = (int)(p & 0x1FFFFu);
    }
}

// ---------------------------------------------------------------------------
// agg1pull: wave per node; lane = es*16+u; 16 edges in flight per iteration
// (4 predicated uint2 gathers per lane before unpacking -> 4x MLP).
// Fused epilogue: h = relu(sum*di + xr); hl = h.W2_l; hr = h.W2_r + b2.
// ---------------------------------------------------------------------------
__global__ __launch_bounds__(256) void agg1pull(const int* __restrict__ start,
                                                const int* __restrict__ cnt,
                                                const int* __restrict__ ssrc,
                                                const uint2* __restrict__ xlb2,
                                                const float* __restrict__ xr,
                                                const float* __restrict__ deg_inv,
                                                const float* __restrict__ w2l,
                                                const float* __restrict__ w2r,
                                                const float* __restrict__ b2,
                                                float* __restrict__ hl,
                                                float* __restrict__ hr) {
    const int gid  = blockIdx.x * 256 + threadIdx.x;
    const int node = gid >> 6;
    const int lane = gid & 63;
    if (node >= N_NODES) return;

    const int s  = start[node];
    const int c  = cnt[node];
    const int es = lane >> 4;   // edge slot 0..3
    const int u  = lane & 15;   // uint2 index within 128B row

    float a0 = 0.f, a1 = 0.f, a2 = 0.f, a3 = 0.f;
    for (int base = 0; base < c; base += 64) {
        const int m = min(c - base, 64);
        int my = 0;
        if (lane < m) my = __builtin_nontemporal_load(&ssrc[s + base + lane]);
        for (int jj = 0; jj < m; jj += 16) {
            const int i0 = jj + es, i1 = jj + 4 + es, i2 = jj + 8 + es, i3 = jj + 12 + es;
            const int s0 = __shfl(my, i0), s1 = __shfl(my, i1);
            const int s2 = __shfl(my, i2), s3 = __shfl(my, i3);
            uint2 v0 = {0u,0u}, v1 = {0u,0u}, v2 = {0u,0u}, v3 = {0u,0u};
            if (i0 < m) v0 = xlb2[(size_t)s0 * 16 + u];
            if (i1 < m) v1 = xlb2[(size_t)s1 * 16 + u];
            if (i2 < m) v2 = xlb2[(size_t)s2 * 16 + u];
            if (i3 < m) v3 = xlb2[(size_t)s3 * 16 + u];
            a0 += __uint_as_float(v0.x << 16);
            a1 += __uint_as_float(v0.x & 0xffff0000u);
            a2 += __uint_as_float(v0.y << 16);
            a3 += __uint_as_float(v0.y & 0xffff0000u);
            a0 += __uint_as_float(v1.x << 16);
            a1 += __uint_as_float(v1.x & 0xffff0000u);
            a2 += __uint_as_float(v1.y << 16);
            a3 += __uint_as_float(v1.y & 0xffff0000u);
            a0 += __uint_as_float(v2.x << 16);
            a1 += __uint_as_float(v2.x & 0xffff0000u);
            a2 += __uint_as_float(v2.y << 16);
            a3 += __uint_as_float(v2.y & 0xffff0000u);
            a0 += __uint_as_float(v3.x << 16);
            a1 += __uint_as_float(v3.x & 0xffff0000u);
            a2 += __uint_as_float(v3.y << 16);
            a3 += __uint_as_float(v3.y & 0xffff0000u);
        }
    }
    // fold edge-slot axis (bits 4,5 of lane)
    a0 += __shfl_xor(a0, 16); a1 += __shfl_xor(a1, 16);
    a2 += __shfl_xor(a2, 16); a3 += __shfl_xor(a3, 16);
    a0 += __shfl_xor(a0, 32); a1 += __shfl_xor(a1, 32);
    a2 += __shfl_xor(a2, 32); a3 += __shfl_xor(a3, 32);

    const float di = deg_inv[node];
    const f32x4 xv = *(const f32x4*)&xr[(size_t)node * HID + 4 * u];
    const float h0 = fmaxf(a0 * di + xv.x, 0.f);
    const float h1 = fmaxf(a1 * di + xv.y, 0.f);
    const float h2 = fmaxf(a2 * di + xv.z, 0.f);
    const float h3 = fmaxf(a3 * di + xv.w, 0.f);
    const f32x4 wl = *(const f32x4*)&w2l[4 * u];
    const f32x4 wr = *(const f32x4*)&w2r[4 * u];
    float a = h0 * wl.x + h1 * wl.y + h2 * wl.z + h3 * wl.w;
    float b = h0 * wr.x + h1 * wr.y + h2 * wr.z + h3 * wr.w;
    // fold u axis (bits 0..3)
    a += __shfl_xor(a, 1); b += __shfl_xor(b, 1);
    a += __shfl_xor(a, 2); b += __shfl_xor(b, 2);
    a += __shfl_xor(a, 4); b += __shfl_xor(b, 4);
    a += __shfl_xor(a, 8); b += __shfl_xor(b, 8);

    if (lane == 0) {
        hl[node] = a;
        hr[node] = b + b2[0];
    }
}

// ---------------------------------------------------------------------------
// agg2pull: wave per node. out = sigmoid(sum_j hl[j] * deg_inv + hr)
// ---------------------------------------------------------------------------
__global__ __launch_bounds__(256) void agg2pull(const int* __restrict__ start,
                                                const int* __restrict__ cnt,
                                                const int* __restrict__ sorted_src,
                                                const float* __restrict__ hl,
                                                const float* __restrict__ hr,
                                                const float* __restrict__ deg_inv,
                                                float* __restrict__ out) {
    const int gid  = blockIdx.x * 256 + threadIdx.x;
    const int node = gid >> 6;
    const int lane = gid & 63;
    if (node >= N_NODES) return;

    const int s = start[node];
    const int c = cnt[node];

    float sum = 0.0f;
    for (int j = lane; j < c; j += 64) {
        sum += hl[__builtin_nontemporal_load(&sorted_src[s + j])];
    }
    #pragma unroll
    for (int off = 32; off; off >>= 1) sum += __shfl_xor(sum, off);

    if (lane == 0) {
        const float z = sum * deg_inv[node] + hr[node];
        out[node] = 1.0f / (1.0f + expf(-z));
    }
}

extern "C" void kernel_launch(void* const* d_in, const int* in_sizes, int n_in,
                              void* d_out, int out_size, void* d_ws, size_t ws_size,
                              hipStream_t stream) {
    const float* x    = (const float*)d_in[0];
    const int*   ei   = (const int*)  d_in[1];
    const float* W1l  = (const float*)d_in[2];
    const float* b1   = (const float*)d_in[3];
    const float* W1r  = (const float*)d_in[4];
    const float* W2l  = (const float*)d_in[5];
    const float* b2   = (const float*)d_in[6];
    const float* W2r  = (const float*)d_in[7];
    float* out = (float*)d_out;

    char* wsb = (char*)d_ws;
    const size_t N = N_NODES;
    uint*     xlb     = (uint*)wsb;      wsb += 32 * N * 4;
    float*    xr      = (float*)wsb;     wsb += 64 * N * 4;
    float*    hl      = (float*)wsb;     wsb += N * 4;
    float*    hr      = (float*)wsb;     wsb += N * 4;
    float*    deg_inv = (float*)wsb;     wsb += N * 4;
    int*      cnt     = (int*)wsb;       wsb += N * 4;
    int*      startA  = (int*)wsb;       wsb += N * 4;
    int*      MT      = (int*)wsb;       wsb += (size_t)MT_LEN * 4;
    int*      MTi     = (int*)wsb;       wsb += (size_t)MT_LEN * 4;
    int*      partial = (int*)wsb;       wsb += 2048 * 4;
    uint*     pairs   = (uint*)wsb;      wsb += (size_t)N_EDGES * 4;
    int*      ssrc    = (int*)wsb;       wsb += (size_t)N_EDGES * 4;
    ushort_t* wpk     = (ushort_t*)wsb;  wsb += 128 * 128 * 2;

    // dense path
    wrepack<<<64, 256, 0, stream>>>(W1l, W1r, wpk);
    gemm1m<<<N_MTILE, 256, 0, stream>>>(x, wpk, b1, xlb, xr);

    // CSR build, atomic-free (LDS only)
    binHist<<<NBLK_BIN, 256, 0, stream>>>(ei, MT);
    scanA2<<<NB_SA2, 256, 0, stream>>>(MT, MTi, partial);
    scanB2<<<1, 1024, 0, stream>>>(partial);
    scanC2<<<NB_SA2, 256, 0, stream>>>(MT, MTi, partial);
    binScatter<<<NBLK_BIN, 256, 0, stream>>>(ei, MTi, pairs);
    bucketCSR<<<BUCKETS, 256, 0, stream>>>(pairs, MTi, startA, cnt, deg_inv, ssrc);

    // pull-aggregations
    {
        const long long total = (long long)N_NODES * 64;
        const int blocks = (int)((total + 255) / 256);
        agg1pull<<<blocks, 256, 0, stream>>>(startA, cnt, ssrc, (const uint2*)xlb,
                                             xr, deg_inv, W2l, W2r, b2, hl, hr);
        agg2pull<<<blocks, 256, 0, stream>>>(startA, cnt, ssrc, hl, hr, deg_inv, out);
    }
}

// Round 10
// 212.761 us; speedup vs baseline: 1.7756x; 1.0402x over previous
//
#include <hip/hip_runtime.h>
#include <math.h>

#define N_NODES 100000
#define N_EDGES 3200000
#define IN_DIM  128
#define HID     64
#define N_MTILE (N_NODES / 16)            // 6250 row-tiles (exact)

// binning-sort geometry
#define E_BLK    4096
#define NBLK_BIN ((N_EDGES + E_BLK - 1) / E_BLK)   // 782
#define BUCKETS  500
#define BRANGE   200                                // 500*200 = 100000 exact
#define MT_LEN   (BUCKETS * NBLK_BIN)               // 391000
#define NB_SA2   ((MT_LEN + 255) / 256)             // 1528 scan blocks (<=2048)

typedef unsigned int  uint;
typedef unsigned short ushort_t;
typedef __attribute__((ext_vector_type(8))) short bf16x8;
typedef __attribute__((ext_vector_type(4))) float f32x4;

// HW packed f32->bf16 (RNE): lo -> bits[15:0], hi -> bits[31:16]
__device__ __forceinline__ uint cvtpk(float lo, float hi) {
    uint r;
    asm("v_cvt_pk_bf16_f32 %0, %1, %2" : "=v"(r) : "v"(lo), "v"(hi));
    return r;
}

// ---------------------------------------------------------------------------
// wrepack: lay W = [W1_l | W1_r] (128x128) out in per-lane B-fragment order
// ---------------------------------------------------------------------------
__global__ __launch_bounds__(256) void wrepack(const float* __restrict__ Wl,
                                               const float* __restrict__ Wr,
                                               ushort_t* __restrict__ wpk) {
    const int idx = blockIdx.x * 256 + threadIdx.x;
    if (idx >= 128 * 128) return;
    const int j = idx & 7;
    const int l = (idx >> 3) & 63;
    const int s = (idx >> 9) & 3;
    const int t = idx >> 11;
    const int row = s * 32 + ((l >> 4) << 3) + j;
    const int col = t * 16 + (l & 15);
    const float v = (col < 64) ? Wl[row * 64 + col] : Wr[row * 64 + (col - 64)];
    uint a = __float_as_uint(v);
    a = (a + 0x7fffu + ((a >> 16) & 1u)) >> 16;
    wpk[idx] = (ushort_t)a;
}

// ---------------------------------------------------------------------------
// gemm1m: MFMA gemm, 1 row-tile per block, 4 waves = 8 col-tiles.
// ---------------------------------------------------------------------------
__global__ __launch_bounds__(256) void gemm1m(const float* __restrict__ x,
                                              const ushort_t* __restrict__ wpk,
                                              const float* __restrict__ b1,
                                              uint* __restrict__ xlb,
                                              float* __restrict__ xr) {
    __shared__ float ax[16][132];
    const int tid  = threadIdx.x;
    const int wid  = tid >> 6;
    const int lane = tid & 63;
    const int t0   = wid * 2;
    const int r16  = lane & 15;
    const int kg   = lane >> 4;

    bf16x8 bf[2][4];
    #pragma unroll
    for (int tt = 0; tt < 2; ++tt)
        #pragma unroll
        for (int s = 0; s < 4; ++s)
            bf[tt][s] = *(const bf16x8*)&wpk[(((size_t)(t0 + tt) * 4 + s) * 64 + lane) * 8];

    float bias[2] = {0.f, 0.f};
    if (wid >= 2) {
        bias[0] = b1[(t0 + 0) * 16 + r16 - 64];
        bias[1] = b1[(t0 + 1) * 16 + r16 - 64];
    }

    const int row0 = blockIdx.x * 16;

    {
        const int r = tid >> 5;
        const int o = tid & 31;
        #pragma unroll
        for (int it = 0; it < 2; ++it) {
            const int rr = it * 8 + r;
            const f32x4 g = __builtin_nontemporal_load(
                (const f32x4*)&x[(size_t)(row0 + rr) * IN_DIM + o * 4]);
            *(f32x4*)&ax[rr][o * 4] = g;
        }
    }
    __syncthreads();

    f32x4 acc[2];
    acc[0] = (f32x4){0.f, 0.f, 0.f, 0.f};
    acc[1] = (f32x4){0.f, 0.f, 0.f, 0.f};

    #pragma unroll
    for (int s = 0; s < 4; ++s) {
        const float* lp = &ax[r16][s * 32 + kg * 8];
        const f32x4 a0 = *(const f32x4*)lp;
        const f32x4 a1 = *(const f32x4*)(lp + 4);
        union { uint u[4]; bf16x8 v; } af;
        af.u[0] = cvtpk(a0.x, a0.y);
        af.u[1] = cvtpk(a0.z, a0.w);
        af.u[2] = cvtpk(a1.x, a1.y);
        af.u[3] = cvtpk(a1.z, a1.w);
        acc[0] = __builtin_amdgcn_mfma_f32_16x16x32_bf16(af.v, bf[0][s], acc[0], 0, 0, 0);
        acc[1] = __builtin_amdgcn_mfma_f32_16x16x32_bf16(af.v, bf[1][s], acc[1], 0, 0, 0);
    }

    if (wid < 2) {
        #pragma unroll
        for (int tt = 0; tt < 2; ++tt) {
            const int col = (t0 + tt) * 16 + r16;
            #pragma unroll
            for (int r = 0; r < 4; ++r) {
                const float mine  = acc[tt][r];
                const float other = __shfl_xor(mine, 1);
                if ((lane & 1) == 0) {
                    const int row = row0 + kg * 4 + r;
                    xlb[(size_t)row * 32 + (col >> 1)] = cvtpk(mine, other);
                }
            }
        }
    } else {
        #pragma unroll
        for (int tt = 0; tt < 2; ++tt) {
            const int c = (t0 + tt) * 16 + r16 - 64;
            #pragma unroll
            for (int r = 0; r < 4; ++r) {
                const int row = row0 + kg * 4 + r;
                xr[(size_t)row * HID + c] = acc[tt][r] + bias[tt];
            }
        }
    }
}

// ---------------------------------------------------------------------------
// binHist: per (edge-block, bucket) histogram via LDS atomics.
// ---------------------------------------------------------------------------
__global__ __launch_bounds__(256) void binHist(const int* __restrict__ ei,
                                               int* __restrict__ MT) {
    __shared__ int h[BUCKETS];
    for (int j = threadIdx.x; j < BUCKETS; j += 256) h[j] = 0;
    __syncthreads();
    const int e0 = blockIdx.x * E_BLK;
    const int e1 = min(e0 + E_BLK, N_EDGES);
    for (int e = e0 + threadIdx.x; e < e1; e += 256)
        atomicAdd(&h[__builtin_nontemporal_load(&ei[N_EDGES + e]) / BRANGE], 1);
    __syncthreads();
    for (int j = threadIdx.x; j < BUCKETS; j += 256)
        MT[j * NBLK_BIN + blockIdx.x] = h[j];
}

// scanA2: per-block EXCLUSIVE scan of MT -> MTi; block totals -> partial.
// Consumers add partial[flat>>8] (no scanC2 pass needed).
__global__ __launch_bounds__(256) void scanA2(const int* __restrict__ MT,
                                              int* __restrict__ MTi,
                                              int* __restrict__ partial) {
    __shared__ int sh[256];
    const int tid = threadIdx.x;
    const int gid = blockIdx.x * 256 + tid;
    int v = (gid < MT_LEN) ? MT[gid] : 0;
    sh[tid] = v;
    __syncthreads();
    for (int off = 1; off < 256; off <<= 1) {
        int t = (tid >= off) ? sh[tid - off] : 0;
        __syncthreads();
        sh[tid] += t;
        __syncthreads();
    }
    if (gid < MT_LEN) MTi[gid] = sh[tid] - v;   // exclusive within block
    if (tid == 255) partial[blockIdx.x] = sh[255];
}

// 2-per-thread scan: capacity 2048 partials
__global__ __launch_bounds__(1024) void scanB2(int* __restrict__ partial) {
    __shared__ int sh[1024];
    const int tid = threadIdx.x;
    const int i0 = 2 * tid, i1 = 2 * tid + 1;
    int v0 = (i0 < NB_SA2) ? partial[i0] : 0;
    int v1 = (i1 < NB_SA2) ? partial[i1] : 0;
    const int s = v0 + v1;
    sh[tid] = s;
    __syncthreads();
    for (int off = 1; off < 1024; off <<= 1) {
        int t = (tid >= off) ? sh[tid - off] : 0;
        __syncthreads();
        sh[tid] += t;
        __syncthreads();
    }
    const int excl = sh[tid] - s;
    if (i0 < NB_SA2) partial[i0] = excl;
    if (i1 < NB_SA2) partial[i1] = excl + v0;
}

// ---------------------------------------------------------------------------
// binScatter (staged): block-local counting sort in LDS, then each bucket's
// run written out contiguously. bktof LDS table replaces binary search.
// ---------------------------------------------------------------------------
__global__ __launch_bounds__(256) void binScatter(const int* __restrict__ ei,
                                                  const int* __restrict__ MTi,
                                                  const int* __restrict__ partial,
                                                  uint* __restrict__ pairs) {
    __shared__ int      hcnt[BUCKETS];
    __shared__ int      lbase[BUCKETS + 1];
    __shared__ int      dbase[BUCKETS];
    __shared__ ushort_t bktof[E_BLK];
    __shared__ uint     staged[E_BLK];
    __shared__ int      sc[256];

    const int tid = threadIdx.x;
    const int e0  = blockIdx.x * E_BLK;
    const int e1  = min(e0 + E_BLK, N_EDGES);
    const int n   = e1 - e0;

    for (int j = tid; j < BUCKETS; j += 256) {
        hcnt[j] = 0;
        const int f = j * NBLK_BIN + blockIdx.x;
        dbase[j] = MTi[f] + partial[f >> 8];       // global base of this run
    }
    __syncthreads();

    // pass 1: load edges, count, remember rank (register-resident)
    uint pk[16]; int bk[16]; int rk[16];
    #pragma unroll
    for (int k = 0; k < 16; ++k) {
        const int e = e0 + k * 256 + tid;
        pk[k] = 0; bk[k] = -1; rk[k] = 0;
        if (e < e1) {
            const int dst = __builtin_nontemporal_load(&ei[N_EDGES + e]);
            const int src = __builtin_nontemporal_load(&ei[e]);
            const int bkt = dst / BRANGE;
            pk[k] = ((uint)(dst - bkt * BRANGE) << 17) | (uint)src;
            bk[k] = bkt;
            rk[k] = atomicAdd(&hcnt[bkt], 1);
        }
    }
    __syncthreads();

    // exclusive scan of hcnt[0..499] (2 per thread over 256 lanes)
    {
        int v0 = 0, v1 = 0;
        if (tid < 250) { v0 = hcnt[2 * tid]; v1 = hcnt[2 * tid + 1]; }
        const int s = v0 + v1;
        sc[tid] = s;
        __syncthreads();
        for (int off = 1; off < 256; off <<= 1) {
            int t = (tid >= off) ? sc[tid - off] : 0;
            __syncthreads();
            sc[tid] += t;
            __syncthreads();
        }
        const int excl = sc[tid] - s;
        if (tid < 250) {
            lbase[2 * tid]     = excl;
            lbase[2 * tid + 1] = excl + v0;
        }
        if (tid == 0) lbase[BUCKETS] = n;
    }
    __syncthreads();

    // place into staged buffer; fill bktof; convert dbase to (gbase - lbase)
    #pragma unroll
    for (int k = 0; k < 16; ++k) {
        if (bk[k] >= 0) staged[lbase[bk[k]] + rk[k]] = pk[k];
    }
    for (int j = tid; j < BUCKETS; j += 256) {
        dbase[j] -= lbase[j];
        const int t1 = lbase[j + 1];
        for (int t = lbase[j]; t < t1; ++t) bktof[t] = (ushort_t)j;
    }
    __syncthreads();

    // write-out: consecutive t -> consecutive dest within a bucket run
    for (int t = tid; t < n; t += 256) {
        const int dest = dbase[bktof[t]] + t;
        __builtin_nontemporal_store(staged[t], &pairs[dest]);
    }
}

// ---------------------------------------------------------------------------
// bucketCSR: one block per bucket (200 nodes). LDS count+scan -> startA/cnt/
// deg_inv, then LDS-cursor scatter of src into final ssrc.
// ---------------------------------------------------------------------------
__global__ __launch_bounds__(256) void bucketCSR(const uint* __restrict__ pairs,
                                                 const int* __restrict__ MTi,
                                                 const int* __restrict__ partial,
                                                 int* __restrict__ startA,
                                                 int* __restrict__ cnt,
                                                 float* __restrict__ deg_inv,
                                                 int* __restrict__ ssrc) {
    __shared__ int h[BRANGE];
    __shared__ int curs[BRANGE];
    __shared__ int sc[256];
    const int tid = threadIdx.x;
    const int b   = blockIdx.x;
    const int n0  = b * BRANGE;

    for (int j = tid; j < BRANGE; j += 256) h[j] = 0;
    __syncthreads();

    const int f0 = b * NBLK_BIN;
    const int bs = MTi[f0] + partial[f0 >> 8];
    int be = N_EDGES;
    if (b + 1 < BUCKETS) {
        const int f1 = (b + 1) * NBLK_BIN;
        be = MTi[f1] + partial[f1 >> 8];
    }

    for (int e = bs + tid; e < be; e += 256)
        atomicAdd(&h[__builtin_nontemporal_load(&pairs[e]) >> 17], 1);
    __syncthreads();

    sc[tid] = (tid < BRANGE) ? h[tid] : 0;
    __syncthreads();
    for (int off = 1; off < 256; off <<= 1) {
        int t = (tid >= off) ? sc[tid - off] : 0;
        __syncthreads();
        sc[tid] += t;
        __syncthreads();
    }
    if (tid < BRANGE) {
        const int c  = h[tid];
        const int st = bs + sc[tid] - c;   // exclusive
        const int node = n0 + tid;
        startA[node]  = st;
        cnt[node]     = c;
        deg_inv[node] = (c > 0) ? (1.0f / (float)c) : 0.0f;
        curs[tid]     = st;
    }
    __syncthreads();

    for (int e = bs + tid; e < be; e += 256) {
        const uint p = __builtin_nontemporal_load(&pairs[e]);
        const int r = atomicAdd(&curs[p >> 17], 1);
        ssrc[r] = (int)(p & 0x1FFFFu);
    }
}

// ---------------------------------------------------------------------------
// agg1pull: wave per node; lane = es*16+u; 32 edges in flight per iteration
// (8 predicated uint2 gathers per lane, static v[8] register window).
// Fused epilogue: h = relu(sum*di + xr); hl = h.W2_l; hr = h.W2_r + b2.
// ---------------------------------------------------------------------------
__global__ __launch_bounds__(256) void agg1pull(const int* __restrict__ start,
                                                const int* __restrict__ cnt,
                                                const int* __restrict__ ssrc,
                                                const uint2* __restrict__ xlb2,
                                                const float* __restrict__ xr,
                                                const float* __restrict__ deg_inv,
                                                const float* __restrict__ w2l,
                                                const float* __restrict__ w2r,
                                                const float* __restrict__ b2,
                                                float* __restrict__ hl,
                                                float* __restrict__ hr) {
    const int gid  = blockIdx.x * 256 + threadIdx.x;
    const int node = gid >> 6;
    const int lane = gid & 63;
    if (node >= N_NODES) return;

    const int s  = start[node];
    const int c  = cnt[node];
    const int es = lane >> 4;   // edge slot 0..3
    const int u  = lane & 15;   // uint2 index within 128B row

    float a0 = 0.f, a1 = 0.f, a2 = 0.f, a3 = 0.f;
    for (int base = 0; base < c; base += 64) {
        const int m = min(c - base, 64);
        int my = 0;
        if (lane < m) my = __builtin_nontemporal_load(&ssrc[s + base + lane]);
        for (int jj = 0; jj < m; jj += 32) {
            uint2 v[8];
            #pragma unroll
            for (int q = 0; q < 8; ++q) {
                const int idx = jj + q * 4 + es;
                const int sp  = __shfl(my, idx & 63);
                if (idx < m) v[q] = xlb2[(size_t)sp * 16 + u];
                else         v[q] = make_uint2(0u, 0u);
            }
            #pragma unroll
            for (int q = 0; q < 8; ++q) {
                a0 += __uint_as_float(v[q].x << 16);
                a1 += __uint_as_float(v[q].x & 0xffff0000u);
                a2 += __uint_as_float(v[q].y << 16);
                a3 += __uint_as_float(v[q].y & 0xffff0000u);
            }
        }
    }
    // fold edge-slot axis (bits 4,5 of lane)
    a0 += __shfl_xor(a0, 16); a1 += __shfl_xor(a1, 16);
    a2 += __shfl_xor(a2, 16); a3 += __shfl_xor(a3, 16);
    a0 += __shfl_xor(a0, 32); a1 += __shfl_xor(a1, 32);
    a2 += __shfl_xor(a2, 32); a3 += __shfl_xor(a3, 32);

    const float di = deg_inv[node];
    const f32x4 xv = *(const f32x4*)&xr[(size_t)node * HID + 4 * u];
    const float h0 = fmaxf(a0 * di + xv.x, 0.f);
    const float h1 = fmaxf(a1 * di + xv.y, 0.f);
    const float h2 = fmaxf(a2 * di + xv.z, 0.f);
    const float h3 = fmaxf(a3 * di + xv.w, 0.f);
    const f32x4 wl = *(const f32x4*)&w2l[4 * u];
    const f32x4 wr = *(const f32x4*)&w2r[4 * u];
    float a = h0 * wl.x + h1 * wl.y + h2 * wl.z + h3 * wl.w;
    float b = h0 * wr.x + h1 * wr.y + h2 * wr.z + h3 * wr.w;
    // fold u axis (bits 0..3)
    a += __shfl_xor(a, 1); b += __shfl_xor(b, 1);
    a += __shfl_xor(a, 2); b += __shfl_xor(b, 2);
    a += __shfl_xor(a, 4); b += __shfl_xor(b, 4);
    a += __shfl_xor(a, 8); b += __shfl_xor(b, 8);

    if (lane == 0) {
        hl[node] = a;
        hr[node] = b + b2[0];
    }
}

// ---------------------------------------------------------------------------
// agg2pull: wave per node. out = sigmoid(sum_j hl[j] * deg_inv + hr)
// ---------------------------------------------------------------------------
__global__ __launch_bounds__(256) void agg2pull(const int* __restrict__ start,
                                                const int* __restrict__ cnt,
                                                const int* __restrict__ sorted_src,
                                                const float* __restrict__ hl,
                                                const float* __restrict__ hr,
                                                const float* __restrict__ deg_inv,
                                                float* __restrict__ out) {
    const int gid  = blockIdx.x * 256 + threadIdx.x;
    const int node = gid >> 6;
    const int lane = gid & 63;
    if (node >= N_NODES) return;

    const int s = start[node];
    const int c = cnt[node];

    float sum = 0.0f;
    for (int j = lane; j < c; j += 64) {
        sum += hl[__builtin_nontemporal_load(&sorted_src[s + j])];
    }
    #pragma unroll
    for (int off = 32; off; off >>= 1) sum += __shfl_xor(sum, off);

    if (lane == 0) {
        const float z = sum * deg_inv[node] + hr[node];
        out[node] = 1.0f / (1.0f + expf(-z));
    }
}

extern "C" void kernel_launch(void* const* d_in, const int* in_sizes, int n_in,
                              void* d_out, int out_size, void* d_ws, size_t ws_size,
                              hipStream_t stream) {
    const float* x    = (const float*)d_in[0];
    const int*   ei   = (const int*)  d_in[1];
    const float* W1l  = (const float*)d_in[2];
    const float* b1   = (const float*)d_in[3];
    const float* W1r  = (const float*)d_in[4];
    const float* W2l  = (const float*)d_in[5];
    const float* b2   = (const float*)d_in[6];
    const float* W2r  = (const float*)d_in[7];
    float* out = (float*)d_out;

    char* wsb = (char*)d_ws;
    const size_t N = N_NODES;
    uint*     xlb     = (uint*)wsb;      wsb += 32 * N * 4;
    float*    xr      = (float*)wsb;     wsb += 64 * N * 4;
    float*    hl      = (float*)wsb;     wsb += N * 4;
    float*    hr      = (float*)wsb;     wsb += N * 4;
    float*    deg_inv = (float*)wsb;     wsb += N * 4;
    int*      cnt     = (int*)wsb;       wsb += N * 4;
    int*      startA  = (int*)wsb;       wsb += N * 4;
    int*      MT      = (int*)wsb;       wsb += (size_t)MT_LEN * 4;
    int*      MTi     = (int*)wsb;       wsb += (size_t)MT_LEN * 4;
    int*      partial = (int*)wsb;       wsb += 2048 * 4;
    uint*     pairs   = (uint*)wsb;      wsb += (size_t)N_EDGES * 4;
    int*      ssrc    = (int*)wsb;       wsb += (size_t)N_EDGES * 4;
    ushort_t* wpk     = (ushort_t*)wsb;  wsb += 128 * 128 * 2;

    // dense path
    wrepack<<<64, 256, 0, stream>>>(W1l, W1r, wpk);
    gemm1m<<<N_MTILE, 256, 0, stream>>>(x, wpk, b1, xlb, xr);

    // CSR build, atomic-free (LDS only)
    binHist<<<NBLK_BIN, 256, 0, stream>>>(ei, MT);
    scanA2<<<NB_SA2, 256, 0, stream>>>(MT, MTi, partial);
    scanB2<<<1, 1024, 0, stream>>>(partial);
    binScatter<<<NBLK_BIN, 256, 0, stream>>>(ei, MTi, partial, pairs);
    bucketCSR<<<BUCKETS, 256, 0, stream>>>(pairs, MTi, partial, startA, cnt, deg_inv, ssrc);

    // pull-aggregations
    {
        const long long total = (long long)N_NODES * 64;
        const int blocks = (int)((total + 255) / 256);
        agg1pull<<<blocks, 256, 0, stream>>>(startA, cnt, ssrc, (const uint2*)xlb,
                                             xr, deg_inv, W2l, W2r, b2, hl, hr);
        agg2pull<<<blocks, 256, 0, stream>>>(startA, cnt, ssrc, hl, hr, deg_inv, out);
    }
}